// Round 1
// baseline (409.633 us; speedup 1.0000x reference)
//
#include <hip/hip_runtime.h>
#include <stdint.h>

#define B_SZ 8192
#define D_SZ 1024
#define L_SZ 64
#define H_SZ 256

#define BM 128
#define BN 256
#define BK 64
#define NSTEP (D_SZ / BK)  // 16

typedef __attribute__((ext_vector_type(8))) __bf16 bf16x8;
typedef __attribute__((ext_vector_type(4))) float f32x4;

typedef __attribute__((address_space(1))) void as1_void;
typedef __attribute__((address_space(3))) void as3_void;

static __device__ __forceinline__ void gload_lds16(const void* g, void* l) {
    __builtin_amdgcn_global_load_lds((as1_void*)g, (as3_void*)l, 16, 0, 0);
}

static __device__ __forceinline__ unsigned short f2bf(float f) {
    uint32_t u = __builtin_bit_cast(uint32_t, f);
    u += 0x7fffu + ((u >> 16) & 1u);
    return (unsigned short)(u >> 16);
}

// ---------------- prep: x (fp32 [B][D]) -> bf16 ----------------
__global__ void cvt_x_kernel(const float* __restrict__ x, unsigned short* __restrict__ xb) {
    int i = blockIdx.x * blockDim.x + threadIdx.x;  // float4 quad index
    const float4 v = reinterpret_cast<const float4*>(x)[i];
    ushort4 o;
    o.x = f2bf(v.x); o.y = f2bf(v.y); o.z = f2bf(v.z); o.w = f2bf(v.w);
    reinterpret_cast<ushort4*>(xb)[i] = o;
}

// ------- prep: W1 (fp32 [L][D][H]) -> W1T bf16 [L][H][D] (transpose) -------
__global__ void transpose_w1_kernel(const float* __restrict__ w1, unsigned short* __restrict__ w1t) {
    __shared__ float tile[64][65];
    int b = blockIdx.x;          // 64 * 16 * 4 = 4096 blocks
    int l  = b >> 6;
    int dt = (b >> 2) & 15;
    int ht = b & 3;
    int tx = threadIdx.x & 63;
    int ty = threadIdx.x >> 6;   // 0..3
    const float* src = w1 + (size_t)l * (D_SZ * H_SZ);
    #pragma unroll
    for (int r = 0; r < 64; r += 4)
        tile[r + ty][tx] = src[(size_t)(dt * 64 + r + ty) * H_SZ + ht * 64 + tx];
    __syncthreads();
    unsigned short* dst = w1t + (size_t)l * (H_SZ * D_SZ);
    #pragma unroll
    for (int r = 0; r < 64; r += 4)
        dst[(size_t)(ht * 64 + r + ty) * D_SZ + dt * 64 + tx] = f2bf(tile[tx][r + ty]);
}

// ---------------- fused label-wise FFN GEMM ----------------
// grid: (B/BM) * L = 64*64 = 4096 blocks, 512 threads (8 waves, 2x4)
__global__ __launch_bounds__(512, 2) void ffn_gemm_kernel(
    const unsigned short* __restrict__ xb,    // bf16 [B][D]
    const unsigned short* __restrict__ w1t,   // bf16 [L][H][D]
    const float* __restrict__ b1,             // [L][H]
    const float* __restrict__ w2,             // [L][H]
    const float* __restrict__ b2,             // [L]
    float* __restrict__ out)                  // [B][L]
{
    __shared__ unsigned short ldsA[2][BM * BK];   // 16 KB per buf
    __shared__ unsigned short ldsB[2][BN * BK];   // 32 KB per buf
    __shared__ float partLds[2][64][4];

    // bijective XCD swizzle (4096 % 8 == 0): each XCD gets 512 contiguous
    // logical wgs = 8 labels x 64 m-tiles -> W1T_l panels stay hot in its L2.
    const int bid = blockIdx.x;
    const int wg  = ((bid & 7) << 9) + (bid >> 3);
    const int l   = wg >> 6;
    const int m0  = (wg & 63) * BM;

    const int tid  = threadIdx.x;
    const int wid  = tid >> 6;
    const int lane = tid & 63;
    const int wr   = wid >> 2;   // 0..1
    const int wc   = wid & 3;    // 0..3

    // Pre-swizzled global source addresses (rule #21): LDS dest is linear
    // (global_load_lds writes base + lane*16); the XOR swizzle
    // slot = kg ^ (row&7) is baked into the per-lane global source.
    const unsigned short* aSrc[2];
    #pragma unroll
    for (int i = 0; i < 2; ++i) {
        int q  = wid * 128 + i * 64 + lane;   // granule 0..1023
        int r  = q >> 3;
        int kg = (q & 7) ^ (r & 7);
        aSrc[i] = xb + (size_t)(m0 + r) * D_SZ + kg * 8;
    }
    const unsigned short* bSrc[4];
    #pragma unroll
    for (int i = 0; i < 4; ++i) {
        int q  = wid * 256 + i * 64 + lane;   // granule 0..2047
        int n  = q >> 3;
        int kg = (q & 7) ^ (n & 7);
        bSrc[i] = w1t + ((size_t)l * H_SZ + n) * D_SZ + kg * 8;
    }

    auto stage = [&](int buf, int t) {
        const int koff = t * BK;
        #pragma unroll
        for (int i = 0; i < 2; ++i)
            gload_lds16(aSrc[i] + koff, &ldsA[buf][(wid * 128 + i * 64) * 8]);
        #pragma unroll
        for (int i = 0; i < 4; ++i)
            gload_lds16(bSrc[i] + koff, &ldsB[buf][(wid * 256 + i * 64) * 8]);
    };

    f32x4 acc[4][4];
    #pragma unroll
    for (int m = 0; m < 4; ++m)
        #pragma unroll
        for (int n = 0; n < 4; ++n) {
            acc[m][n][0] = 0.f; acc[m][n][1] = 0.f;
            acc[m][n][2] = 0.f; acc[m][n][3] = 0.f;
        }

    stage(0, 0);
    __syncthreads();   // drains vmcnt(0)

    const int g  = lane >> 4;
    const int rl = lane & 15;

    for (int t = 0; t < NSTEP; ++t) {
        const int buf = t & 1;
        if (t + 1 < NSTEP) stage(buf ^ 1, t + 1);

        bf16x8 af[2][4], bf[2][4];
        #pragma unroll
        for (int m = 0; m < 4; ++m) {
            const int row = wr * 64 + m * 16 + rl;
            #pragma unroll
            for (int ks = 0; ks < 2; ++ks) {
                const int slot = (ks * 4 + g) ^ (row & 7);
                af[ks][m] = *reinterpret_cast<const bf16x8*>(
                    reinterpret_cast<const char*>(&ldsA[buf][0]) + row * 128 + slot * 16);
            }
        }
        #pragma unroll
        for (int n = 0; n < 4; ++n) {
            const int col = wc * 64 + n * 16 + rl;
            #pragma unroll
            for (int ks = 0; ks < 2; ++ks) {
                const int slot = (ks * 4 + g) ^ (col & 7);
                bf[ks][n] = *reinterpret_cast<const bf16x8*>(
                    reinterpret_cast<const char*>(&ldsB[buf][0]) + col * 128 + slot * 16);
            }
        }
        #pragma unroll
        for (int ks = 0; ks < 2; ++ks)
            #pragma unroll
            for (int m = 0; m < 4; ++m)
                #pragma unroll
                for (int n = 0; n < 4; ++n)
                    acc[m][n] = __builtin_amdgcn_mfma_f32_16x16x32_bf16(
                        af[ks][m], bf[ks][n], acc[m][n], 0, 0, 0);

        __syncthreads();   // drains vmcnt for staged next buffer + lgkm
    }

    // ---- fused epilogue: out[row, l] = sum_h relu(C + b1)*w2 + b2 ----
    float b1v[4], w2v[4];
    #pragma unroll
    for (int n = 0; n < 4; ++n) {
        const int col = wc * 64 + n * 16 + rl;
        b1v[n] = b1[l * H_SZ + col];
        w2v[n] = w2[l * H_SZ + col];
    }
    #pragma unroll
    for (int m = 0; m < 4; ++m) {
        #pragma unroll
        for (int r = 0; r < 4; ++r) {
            float p = 0.f;
            #pragma unroll
            for (int n = 0; n < 4; ++n) {
                float v = acc[m][n][r] + b1v[n];
                v = fmaxf(v, 0.f);
                p += v * w2v[n];
            }
            p += __shfl_xor(p, 1);
            p += __shfl_xor(p, 2);
            p += __shfl_xor(p, 4);
            p += __shfl_xor(p, 8);
            if ((lane & 15) == 0)
                partLds[wr][m * 16 + (lane >> 4) * 4 + r][wc] = p;
        }
    }
    __syncthreads();
    if (tid < BM) {
        float s = b2[l];
        #pragma unroll
        for (int w = 0; w < 4; ++w) s += partLds[tid >> 6][tid & 63][w];
        out[(size_t)(m0 + tid) * L_SZ + l] = s;
    }
}

extern "C" void kernel_launch(void* const* d_in, const int* in_sizes, int n_in,
                              void* d_out, int out_size, void* d_ws, size_t ws_size,
                              hipStream_t stream) {
    const float* x  = (const float*)d_in[0];
    const float* W1 = (const float*)d_in[1];
    const float* b1 = (const float*)d_in[2];
    const float* W2 = (const float*)d_in[3];
    const float* b2 = (const float*)d_in[4];
    float* out = (float*)d_out;

    unsigned short* xb  = (unsigned short*)d_ws;                 // 16 MB
    unsigned short* w1t = xb + (size_t)B_SZ * D_SZ;              // 32 MB

    cvt_x_kernel<<<(B_SZ * D_SZ / 4) / 256, 256, 0, stream>>>(x, xb);
    transpose_w1_kernel<<<L_SZ * 16 * 4, 256, 0, stream>>>(W1, w1t);
    ffn_gemm_kernel<<<(B_SZ / BM) * L_SZ, 512, 0, stream>>>(xb, w1t, b1, W2, b2, out);
}

// Round 2
// 294.347 us; speedup vs baseline: 1.3917x; 1.3917x over previous
//
#include <hip/hip_runtime.h>
#include <stdint.h>

#define B_SZ 8192
#define D_SZ 1024
#define L_SZ 64
#define H_SZ 256

#define BM 256
#define BN 256
#define BK 64
#define NT (D_SZ / BK)   // 16 K-tiles, 8 iterations x 2

typedef __attribute__((ext_vector_type(8))) __bf16 bf16x8;
typedef __attribute__((ext_vector_type(4))) float f32x4;

typedef __attribute__((address_space(1))) void as1_void;
typedef __attribute__((address_space(3))) void as3_void;

static __device__ __forceinline__ void gload_lds16(const void* g, void* l) {
    __builtin_amdgcn_global_load_lds((as1_void*)g, (as3_void*)l, 16, 0, 0);
}

static __device__ __forceinline__ unsigned short f2bf(float f) {
    uint32_t u = __builtin_bit_cast(uint32_t, f);
    u += 0x7fffu + ((u >> 16) & 1u);
    return (unsigned short)(u >> 16);
}

// ---------------- prep: x (fp32 [B][D]) -> bf16 ----------------
__global__ void cvt_x_kernel(const float* __restrict__ x, unsigned short* __restrict__ xb) {
    int i = blockIdx.x * blockDim.x + threadIdx.x;
    const float4 v = reinterpret_cast<const float4*>(x)[i];
    ushort4 o;
    o.x = f2bf(v.x); o.y = f2bf(v.y); o.z = f2bf(v.z); o.w = f2bf(v.w);
    reinterpret_cast<ushort4*>(xb)[i] = o;
}

// ------- prep: W1 (fp32 [L][D][H]) -> W1T bf16 [L][H][D] -------
__global__ void transpose_w1_kernel(const float* __restrict__ w1, unsigned short* __restrict__ w1t) {
    __shared__ float tile[64][65];
    int b = blockIdx.x;
    int l  = b >> 6;
    int dt = (b >> 2) & 15;
    int ht = b & 3;
    int tx = threadIdx.x & 63;
    int ty = threadIdx.x >> 6;
    const float* src = w1 + (size_t)l * (D_SZ * H_SZ);
    #pragma unroll
    for (int r = 0; r < 64; r += 4)
        tile[r + ty][tx] = src[(size_t)(dt * 64 + r + ty) * H_SZ + ht * 64 + tx];
    __syncthreads();
    unsigned short* dst = w1t + (size_t)l * (H_SZ * D_SZ);
    #pragma unroll
    for (int r = 0; r < 64; r += 4)
        dst[(size_t)(ht * 64 + r + ty) * D_SZ + dt * 64 + tx] = f2bf(tile[tx][r + ty]);
}

// ---------------- fused label-wise FFN GEMM, 256x256 8-phase ----------------
// grid: (B/256) * L = 32*64 = 2048 blocks, 512 threads (8 waves, 2M x 4N)

#define SBAR asm volatile("s_barrier" ::: "memory")
#define VMW(n) asm volatile("s_waitcnt vmcnt(" #n ")" ::: "memory")

#define DS_READ_A(c, quad) do { \
    _Pragma("unroll") for (int j = 0; j < 2; ++j) { \
        const int rowh = ((quad)*2 + j)*16 + rl; \
        _Pragma("unroll") for (int ks = 0; ks < 2; ++ks) { \
            const int slot = (ks*4 + g) ^ (rowh & 7); \
            af[ks][j] = *reinterpret_cast<const bf16x8*>( \
                reinterpret_cast<const char*>(&ldsAB[c][0][wr][0]) + rowh*128 + slot*16); \
        } } } while(0)

#define DS_READ_B(c) do { \
    _Pragma("unroll") for (int nf = 0; nf < 4; ++nf) { \
        const int rowb = wc*64 + nf*16 + rl; \
        const int bh = rowb >> 7; \
        const int rowh = rowb & 127; \
        _Pragma("unroll") for (int ks = 0; ks < 2; ++ks) { \
            const int slot = (ks*4 + g) ^ (rowh & 7); \
            bf[ks][nf] = *reinterpret_cast<const bf16x8*>( \
                reinterpret_cast<const char*>(&ldsAB[c][1][bh][0]) + rowh*128 + slot*16); \
        } } } while(0)

#define MFMA_QUAD(quad) do { \
    __builtin_amdgcn_s_setprio(1); \
    _Pragma("unroll") for (int ks = 0; ks < 2; ++ks) \
    _Pragma("unroll") for (int j = 0; j < 2; ++j) \
    _Pragma("unroll") for (int nf = 0; nf < 4; ++nf) \
        acc[(quad)*2 + j][nf] = __builtin_amdgcn_mfma_f32_16x16x32_bf16( \
            af[ks][j], bf[ks][nf], acc[(quad)*2 + j][nf], 0, 0, 0); \
    __builtin_amdgcn_s_setprio(0); } while(0)

#define STAGE_A(t, h) do { \
    gload_lds16(aSrc[h][0] + (size_t)(t)*BK, &ldsAB[(t)&1][0][h][(wid*64)*8]); \
    gload_lds16(aSrc[h][1] + (size_t)(t)*BK, &ldsAB[(t)&1][0][h][(512 + wid*64)*8]); } while(0)

#define STAGE_B(t, h) do { \
    gload_lds16(bSrc[h][0] + (size_t)(t)*BK, &ldsAB[(t)&1][1][h][(wid*64)*8]); \
    gload_lds16(bSrc[h][1] + (size_t)(t)*BK, &ldsAB[(t)&1][1][h][(512 + wid*64)*8]); } while(0)

__global__ __launch_bounds__(512, 2) void ffn_gemm_kernel(
    const unsigned short* __restrict__ xb,    // bf16 [B][D]
    const unsigned short* __restrict__ w1t,   // bf16 [L][H][D]
    const float* __restrict__ b1,             // [L][H]
    const float* __restrict__ w2,             // [L][H]
    const float* __restrict__ b2,             // [L]
    float* __restrict__ out)                  // [B][L]
{
    // [dbuf][A=0/B=1][half][128 rows * 64 K] bf16 = 128 KiB
    __shared__ unsigned short ldsAB[2][2][2][128 * 64];

    // bijective XCD swizzle (2048 % 8 == 0): XCD x gets 256 contiguous wgs;
    // within an XCD, 32 consecutive wgs share one label -> W1T_l panel (512 KB)
    // stays hot in that XCD's L2 while sweeping x m-tiles.
    const int bid = blockIdx.x;
    const int wg  = ((bid & 7) << 8) + (bid >> 3);
    const int l   = wg >> 5;
    const int m0  = (wg & 31) * BM;

    const int tid  = threadIdx.x;
    const int wid  = tid >> 6;
    const int lane = tid & 63;
    const int wr   = wid >> 2;   // 0..1  (A half = wr)
    const int wc   = wid & 3;    // 0..3
    const int g    = lane >> 4;  // 0..3
    const int rl   = lane & 15;

    // Pre-swizzled global sources (rule #21): LDS dest is linear (base+lane*16);
    // the XOR swizzle slot = kg ^ (row&7) is baked into the per-lane source.
    const unsigned short* aSrc[2][2];
    const unsigned short* bSrc[2][2];
    #pragma unroll
    for (int h = 0; h < 2; ++h)
        #pragma unroll
        for (int c2 = 0; c2 < 2; ++c2) {
            const int q  = c2 * 512 + tid;     // granule within half [0,1024)
            const int r  = q >> 3;             // row within half [0,128)
            const int kg = (q & 7) ^ (r & 7);  // swizzled K-granule
            aSrc[h][c2] = xb  + (size_t)(m0 + h * 128 + r) * D_SZ + kg * 8;
            bSrc[h][c2] = w1t + ((size_t)l * H_SZ + h * 128 + r) * D_SZ + kg * 8;
        }

    f32x4 acc[8][4];
    #pragma unroll
    for (int m = 0; m < 8; ++m)
        #pragma unroll
        for (int n = 0; n < 4; ++n) {
            acc[m][n][0] = 0.f; acc[m][n][1] = 0.f;
            acc[m][n][2] = 0.f; acc[m][n][3] = 0.f;
        }

    bf16x8 af[2][2], bf[2][4];

    // Prologue: stage B(0), A(0), B(1) = 6 half-tiles (12 loads).
    STAGE_B(0, 0); STAGE_B(0, 1);
    STAGE_A(0, 0); STAGE_A(0, 1);
    STAGE_B(1, 0); STAGE_B(1, 1);
    VMW(4);   // tile 0 fully landed; B(1) (2 halves = 4 loads) may be in flight
    SBAR;

    // Main loop: iteration i computes K-tiles 2i (buf0, phases 0-3) and
    // 2i+1 (buf1, phases 4-7); stages A(2i+1), full tile 2i+2, B(2i+3).
    // vmcnt(4) only at phase 3 / phase 7 ends — never a full drain.
    #pragma unroll 1
    for (int i = 0; i < 7; ++i) {
        const int t1 = 2 * i + 1, t2 = 2 * i + 2, t3 = 2 * i + 3;
        // P0
        DS_READ_B(0); DS_READ_A(0, 0); STAGE_A(t1, 0); SBAR; MFMA_QUAD(0); SBAR;
        // P1
        DS_READ_A(0, 1); STAGE_A(t1, 1); SBAR; MFMA_QUAD(1); SBAR;
        // P2
        DS_READ_A(0, 2); STAGE_B(t2, 0); SBAR; MFMA_QUAD(2); SBAR;
        // P3
        DS_READ_A(0, 3); STAGE_B(t2, 1); SBAR; MFMA_QUAD(3); VMW(4); SBAR;
        // P4
        DS_READ_B(1); DS_READ_A(1, 0); STAGE_A(t2, 0); SBAR; MFMA_QUAD(0); SBAR;
        // P5
        DS_READ_A(1, 1); STAGE_A(t2, 1); SBAR; MFMA_QUAD(1); SBAR;
        // P6
        DS_READ_A(1, 2); STAGE_B(t3, 0); SBAR; MFMA_QUAD(2); SBAR;
        // P7
        DS_READ_A(1, 3); STAGE_B(t3, 1); SBAR; MFMA_QUAD(3); VMW(4); SBAR;
    }
    // Tail iteration (tiles 14, 15): only A(15) left to stage.
    DS_READ_B(0); DS_READ_A(0, 0); STAGE_A(15, 0); SBAR; MFMA_QUAD(0); SBAR;
    DS_READ_A(0, 1); STAGE_A(15, 1); SBAR; MFMA_QUAD(1); SBAR;
    DS_READ_A(0, 2); SBAR; MFMA_QUAD(2); SBAR;
    DS_READ_A(0, 3); SBAR; MFMA_QUAD(3); VMW(0); SBAR;
    DS_READ_B(1); DS_READ_A(1, 0); SBAR; MFMA_QUAD(0); SBAR;
    DS_READ_A(1, 1); SBAR; MFMA_QUAD(1); SBAR;
    DS_READ_A(1, 2); SBAR; MFMA_QUAD(2); SBAR;
    DS_READ_A(1, 3); SBAR; MFMA_QUAD(3); SBAR;

    // ---- fused epilogue: out[row, l] = sum_h relu(C + b1)*w2 + b2 ----
    float b1v[4], w2v[4];
    #pragma unroll
    for (int nf = 0; nf < 4; ++nf) {
        const int col = wc * 64 + nf * 16 + rl;
        b1v[nf] = b1[l * H_SZ + col];
        w2v[nf] = w2[l * H_SZ + col];
    }
    __syncthreads();   // loop fully done; safe to reuse LDS
    float* partLds = (float*)&ldsAB[0][0][0][0];   // [2][128][4]
    #pragma unroll
    for (int mf = 0; mf < 8; ++mf) {
        #pragma unroll
        for (int r = 0; r < 4; ++r) {
            float p = 0.f;
            #pragma unroll
            for (int nf = 0; nf < 4; ++nf) {
                float v = acc[mf][nf][r] + b1v[nf];
                v = fmaxf(v, 0.f);
                p += v * w2v[nf];
            }
            p += __shfl_xor(p, 1);
            p += __shfl_xor(p, 2);
            p += __shfl_xor(p, 4);
            p += __shfl_xor(p, 8);
            if (rl == 0)
                partLds[((wr * 128) + mf * 16 + g * 4 + r) * 4 + wc] = p;
        }
    }
    __syncthreads();
    if (tid < BM) {
        float s = b2[l];
        #pragma unroll
        for (int w = 0; w < 4; ++w) s += partLds[tid * 4 + w];
        out[(size_t)(m0 + tid) * L_SZ + l] = s;
    }
}

extern "C" void kernel_launch(void* const* d_in, const int* in_sizes, int n_in,
                              void* d_out, int out_size, void* d_ws, size_t ws_size,
                              hipStream_t stream) {
    const float* x  = (const float*)d_in[0];
    const float* W1 = (const float*)d_in[1];
    const float* b1 = (const float*)d_in[2];
    const float* W2 = (const float*)d_in[3];
    const float* b2 = (const float*)d_in[4];
    float* out = (float*)d_out;

    unsigned short* xb  = (unsigned short*)d_ws;                 // 16 MB
    unsigned short* w1t = xb + (size_t)B_SZ * D_SZ;              // 32 MB

    cvt_x_kernel<<<(B_SZ * D_SZ / 4) / 256, 256, 0, stream>>>(x, xb);
    transpose_w1_kernel<<<L_SZ * 16 * 4, 256, 0, stream>>>(W1, w1t);
    ffn_gemm_kernel<<<(B_SZ / BM) * L_SZ, 512, 0, stream>>>(xb, w1t, b1, W2, b2, out);
}